// Round 7
// baseline (49.571 us; speedup 1.0000x reference)
//
#include <hip/hip_runtime.h>
#include <math.h>

#define NS 4096
#define DD 768
#define NH 30          // N_HIPER
#define NCH 31         // channels per cell
#define NCELL 81       // 9x9 grid
#define NBLK 512       // chunk blocks
#define NTHR 192       // threads (each owns 4 d's)
#define CS 8           // samples per chunk = NS/NBLK
#define NPART 6        // sample partitions for wacc
#define SPP 683        // ceil(NS/NPART)
#define NW (NCELL*DD)
#define NACC (NCELL*NPART)   // 486 wacc blocks

// ---------------------------------------------------------------------------
// k1 pass1: prep + density gather + chunk-local u[s,d] = exp(-l)(1-exp(-dd))
//           (telescoping) + chunk attenuation E[c,d] = exp(-sum dd).
//           Also zeroes W and writes cells/coefs for wacc.
// ---------------------------------------------------------------------------
__global__ __launch_bounds__(NTHR) void pass1_kernel(
    const float* __restrict__ samples, const float* __restrict__ last_point,
    const float* __restrict__ emb,
    int4* __restrict__ cells, float4* __restrict__ coefs,
    float* __restrict__ u, float* __restrict__ Ebuf,
    float* __restrict__ W)
{
    __shared__ int4   s_cells[CS];
    __shared__ float4 s_coefs[CS];
    __shared__ float  s_dist[CS];

    const int t  = threadIdx.x;
    const int b  = blockIdx.x;
    const int d0 = 4*t;

    if (t < CS) {
        const int s = b*CS + t;
        float x = samples[2*s+0], y = samples[2*s+1];
        float xs = x + 4.0f, ys = y + 4.0f;
        int fx = (int)floorf(xs), cx = (int)ceilf(xs);
        int fy = (int)floorf(ys), cy = (int)ceilf(ys);
        float dx = x - floorf(x), dy = y - floorf(y);
        float nx, ny;
        if (s == NS-1) { nx = last_point[0]; ny = last_point[1]; }
        else           { nx = samples[2*s+2]; ny = samples[2*s+3]; }
        float ex = nx - x, ey = ny - y;
        s_dist[t] = sqrtf(ex*ex + ey*ey);
        int4 cl = make_int4(fx*9+fy, cx*9+fy, fx*9+cy, cx*9+cy);
        float4 cf = make_float4((1.f-dx)*(1.f-dy), dx*(1.f-dy),
                                (1.f-dx)*dy,       dx*dy);
        s_cells[t] = cl; s_coefs[t] = cf;
        cells[s] = cl;   coefs[s]  = cf;     // for wacc
    }
    {   // zero W (stream-ordered: wacc dispatched later)
        int g = b*NTHR + t; if (g < NW) W[g] = 0.f;
    }
    __syncthreads();

    float4 E = make_float4(1.f, 1.f, 1.f, 1.f);
    #pragma unroll
    for (int i = 0; i < CS; ++i) {
        int4 cl = s_cells[i]; float4 cf = s_coefs[i]; float dist = s_dist[i];
        const int off = NH*DD + d0;
        float4 e0 = *(const float4*)(emb + cl.x*NCH*DD + off);
        float4 e1 = *(const float4*)(emb + cl.y*NCH*DD + off);
        float4 e2 = *(const float4*)(emb + cl.z*NCH*DD + off);
        float4 e3 = *(const float4*)(emb + cl.w*NCH*DD + off);
        float vx = e0.x*cf.x + e1.x*cf.y + e2.x*cf.z + e3.x*cf.w;
        float vy = e0.y*cf.x + e1.y*cf.y + e2.y*cf.z + e3.y*cf.w;
        float vz = e0.z*cf.x + e1.z*cf.y + e2.z*cf.z + e3.z*cf.w;
        float vw = e0.w*cf.x + e1.w*cf.y + e2.w*cf.z + e3.w*cf.w;
        float fx_ = __expf(-fmaxf(vx, 0.f) * dist);
        float fy_ = __expf(-fmaxf(vy, 0.f) * dist);
        float fz_ = __expf(-fmaxf(vz, 0.f) * dist);
        float fw_ = __expf(-fmaxf(vw, 0.f) * dist);
        *(float4*)(u + (b*CS + i)*DD + d0) =
            make_float4(E.x*(1.f-fx_), E.y*(1.f-fy_),
                        E.z*(1.f-fz_), E.w*(1.f-fw_));
        E.x *= fx_; E.y *= fy_; E.z *= fz_; E.w *= fw_;
    }
    *(float4*)(Ebuf + b*DD + d0) = E;
}

// ---------------------------------------------------------------------------
// k2 scan: exclusive PRODUCT scan of E over 512 chunks per d -> scale[c,d]
// one wave per d; lane handles 8 chunks
// ---------------------------------------------------------------------------
__global__ __launch_bounds__(64) void scan_kernel(
    const float* __restrict__ Ebuf, float* __restrict__ scale) {
    const int d    = blockIdx.x;       // 0..767
    const int lane = threadIdx.x;      // 0..63
    float v[8];
    float tot = 1.f;
    #pragma unroll
    for (int k = 0; k < 8; ++k) {
        v[k] = Ebuf[(lane*8 + k)*DD + d];
        tot *= v[k];
    }
    // inclusive product scan across lanes
    float x = tot;
    #pragma unroll
    for (int off = 1; off < 64; off <<= 1) {
        float y = __shfl_up(x, off);
        if (lane >= off) x *= y;
    }
    // exclusive: shift by one lane
    float run = __shfl_up(x, 1);
    if (lane == 0) run = 1.f;
    #pragma unroll
    for (int k = 0; k < 8; ++k) {
        scale[(lane*8 + k)*DD + d] = run;
        run *= v[k];
    }
}

// ---------------------------------------------------------------------------
// k3 wacc: W[g,d] += sum over samples with corner g of coef*scale[c(s),d]*u
// ---------------------------------------------------------------------------
__global__ __launch_bounds__(NTHR) void wacc_kernel(
    const int4* __restrict__ cells, const float4* __restrict__ coefs,
    const float* __restrict__ u, const float* __restrict__ scale,
    float* __restrict__ W) {
    __shared__ int   s_idx[SPP];
    __shared__ float s_cf[SPP];
    __shared__ int   s_cnt;
    const int g    = blockIdx.x / NPART;
    const int part = blockIdx.x % NPART;
    const int t    = threadIdx.x;
    const int d0   = 4*t;
    if (t == 0) s_cnt = 0;
    __syncthreads();
    const int s_beg = part * SPP;
    const int s_end = min(NS, s_beg + SPP);
    for (int s = s_beg + t; s < s_end; s += NTHR) {
        int4 cl = cells[s]; float4 cf = coefs[s];
        float c = 0.f;
        if (cl.x == g) c += cf.x;
        if (cl.y == g) c += cf.y;
        if (cl.z == g) c += cf.z;
        if (cl.w == g) c += cf.w;
        if (c != 0.f) {
            int idx = atomicAdd(&s_cnt, 1);
            s_idx[idx] = s;
            s_cf[idx]  = c;
        }
    }
    __syncthreads();
    const int cnt = s_cnt;
    float4 a = make_float4(0.f, 0.f, 0.f, 0.f);
    for (int j = 0; j < cnt; ++j) {
        const int   s = s_idx[j];
        const float c = s_cf[j];
        const int   ch = s >> 3;           // s / CS
        float4 uv = *(const float4*)(u + (long)s*DD + d0);
        float4 sc = *(const float4*)(scale + (long)ch*DD + d0);
        a.x += c * sc.x * uv.x;
        a.y += c * sc.y * uv.y;
        a.z += c * sc.z * uv.z;
        a.w += c * sc.w * uv.w;
    }
    atomicAdd(&W[g*DD + d0 + 0], a.x);
    atomicAdd(&W[g*DD + d0 + 1], a.y);
    atomicAdd(&W[g*DD + d0 + 2], a.z);
    atomicAdd(&W[g*DD + d0 + 3], a.w);
}

// ---------------------------------------------------------------------------
// k4 final: out[n,d] = sum_g W[g,d] * T[g,n,d]
// ---------------------------------------------------------------------------
__global__ __launch_bounds__(NTHR) void final_kernel(
    const float* __restrict__ emb, const float* __restrict__ W,
    float* __restrict__ out) {
    const int n  = blockIdx.x;
    const int d0 = 4*threadIdx.x;
    float4 a = make_float4(0.f, 0.f, 0.f, 0.f);
    #pragma unroll 3
    for (int g = 0; g < NCELL; ++g) {
        float4 Wv = *(const float4*)(W + g*DD + d0);
        float4 Tv = *(const float4*)(emb + (g*NCH + n)*DD + d0);
        a.x += Wv.x*Tv.x;
        a.y += Wv.y*Tv.y;
        a.z += Wv.z*Tv.z;
        a.w += Wv.w*Tv.w;
    }
    *(float4*)(out + n*DD + d0) = a;
}

// ---------------------------------------------------------------------------
extern "C" void kernel_launch(void* const* d_in, const int* in_sizes, int n_in,
                              void* d_out, int out_size, void* d_ws, size_t ws_size,
                              hipStream_t stream) {
    const float* samples    = (const float*)d_in[0];
    const float* last_point = (const float*)d_in[1];
    const float* emb        = (const float*)d_in[2];
    float* out = (float*)d_out;

    char* ws = (char*)d_ws;
    int4*   cells = (int4*)ws;     ws += (size_t)NS*sizeof(int4);
    float4* coefs = (float4*)ws;   ws += (size_t)NS*sizeof(float4);
    float*  Ebuf  = (float*)ws;    ws += (size_t)NBLK*DD*sizeof(float);
    float*  scale = (float*)ws;    ws += (size_t)NBLK*DD*sizeof(float);
    float*  Wbuf  = (float*)ws;    ws += (size_t)NW*sizeof(float);
    float*  umat  = (float*)ws;    ws += (size_t)NS*DD*sizeof(float);

    pass1_kernel<<<NBLK, NTHR, 0, stream>>>(samples, last_point, emb,
                                            cells, coefs, umat, Ebuf, Wbuf);
    scan_kernel<<<DD, 64, 0, stream>>>(Ebuf, scale);
    wacc_kernel<<<NACC, NTHR, 0, stream>>>(cells, coefs, umat, scale, Wbuf);
    final_kernel<<<NH, NTHR, 0, stream>>>(emb, Wbuf, out);
}

// Round 8
// 40.936 us; speedup vs baseline: 1.2109x; 1.2109x over previous
//
#include <hip/hip_runtime.h>
#include <math.h>

#define NS 4096
#define DD 768
#define NH 30          // N_HIPER
#define NCH 31         // channels per cell
#define NCELL 81       // 9x9 grid
#define NBLK 256       // chunk blocks
#define NTHR 384       // threads (each owns 2 d's)
#define CS 16          // samples per chunk = NS/NBLK
#define NPART 6        // sample partitions for wacc
#define SPP 683        // ceil(NS/NPART)
#define NW (NCELL*DD)
#define NACC (NCELL*NPART)   // 486 wacc blocks

// ---------------------------------------------------------------------------
// k1 pass1: prep + density gather + chunk-local u[s,d] = E*(1-exp(-dd))
//           (telescoping, E = running exp(-sum dd) within chunk) +
//           chunk attenuation E[c,d]. Also zeroes W, writes cells/coefs.
// ---------------------------------------------------------------------------
__global__ __launch_bounds__(NTHR) void pass1_kernel(
    const float* __restrict__ samples, const float* __restrict__ last_point,
    const float* __restrict__ emb,
    int4* __restrict__ cells, float4* __restrict__ coefs,
    float* __restrict__ u, float* __restrict__ Ebuf,
    float* __restrict__ W)
{
    __shared__ int4   s_cells[CS];
    __shared__ float4 s_coefs[CS];
    __shared__ float  s_dist[CS];

    const int t  = threadIdx.x;
    const int b  = blockIdx.x;
    const int d0 = 2*t;

    if (t < CS) {
        const int s = b*CS + t;
        float x = samples[2*s+0], y = samples[2*s+1];
        float xs = x + 4.0f, ys = y + 4.0f;
        int fx = (int)floorf(xs), cx = (int)ceilf(xs);
        int fy = (int)floorf(ys), cy = (int)ceilf(ys);
        float dx = x - floorf(x), dy = y - floorf(y);
        float nx, ny;
        if (s == NS-1) { nx = last_point[0]; ny = last_point[1]; }
        else           { nx = samples[2*s+2]; ny = samples[2*s+3]; }
        float ex = nx - x, ey = ny - y;
        s_dist[t] = sqrtf(ex*ex + ey*ey);
        int4 cl = make_int4(fx*9+fy, cx*9+fy, fx*9+cy, cx*9+cy);
        float4 cf = make_float4((1.f-dx)*(1.f-dy), dx*(1.f-dy),
                                (1.f-dx)*dy,       dx*dy);
        s_cells[t] = cl; s_coefs[t] = cf;
        cells[s] = cl;   coefs[s]  = cf;     // for wacc
    }
    { int g = b*NTHR + t; if (g < NW) W[g] = 0.f; }   // zero W, no memset
    __syncthreads();

    float Ex = 1.f, Ey = 1.f;
    #pragma unroll
    for (int i = 0; i < CS; ++i) {
        int4 cl = s_cells[i]; float4 cf = s_coefs[i]; float dist = s_dist[i];
        const int off = NH*DD + d0;
        float2 e0 = *(const float2*)(emb + cl.x*NCH*DD + off);
        float2 e1 = *(const float2*)(emb + cl.y*NCH*DD + off);
        float2 e2 = *(const float2*)(emb + cl.z*NCH*DD + off);
        float2 e3 = *(const float2*)(emb + cl.w*NCH*DD + off);
        float vx = e0.x*cf.x + e1.x*cf.y + e2.x*cf.z + e3.x*cf.w;
        float vy = e0.y*cf.x + e1.y*cf.y + e2.y*cf.z + e3.y*cf.w;
        float fx_ = __expf(-fmaxf(vx, 0.f) * dist);
        float fy_ = __expf(-fmaxf(vy, 0.f) * dist);
        *(float2*)(u + (b*CS + i)*DD + d0) =
            make_float2(Ex*(1.f - fx_), Ey*(1.f - fy_));
        Ex *= fx_; Ey *= fy_;
    }
    *(float2*)(Ebuf + b*DD + d0) = make_float2(Ex, Ey);
}

// ---------------------------------------------------------------------------
// k2 scan: exclusive PRODUCT scan of E over 256 chunks per d -> scale[c,d]
// one wave per d; lane handles 4 chunks
// ---------------------------------------------------------------------------
__global__ __launch_bounds__(64) void scan_kernel(
    const float* __restrict__ Ebuf, float* __restrict__ scale) {
    const int d    = blockIdx.x;       // 0..767
    const int lane = threadIdx.x;      // 0..63
    float v[4];
    float tot = 1.f;
    #pragma unroll
    for (int k = 0; k < 4; ++k) {
        v[k] = Ebuf[(lane*4 + k)*DD + d];
        tot *= v[k];
    }
    // inclusive product scan across lanes
    float x = tot;
    #pragma unroll
    for (int off = 1; off < 64; off <<= 1) {
        float y = __shfl_up(x, off);
        if (lane >= off) x *= y;
    }
    // exclusive: shift by one lane
    float run = __shfl_up(x, 1);
    if (lane == 0) run = 1.f;
    #pragma unroll
    for (int k = 0; k < 4; ++k) {
        scale[(lane*4 + k)*DD + d] = run;
        run *= v[k];
    }
}

// ---------------------------------------------------------------------------
// k3 wacc: W[g,d] += sum over samples with corner g of coef*scale[c(s),d]*u
// ---------------------------------------------------------------------------
__global__ __launch_bounds__(256) void wacc_kernel(
    const int4* __restrict__ cells, const float4* __restrict__ coefs,
    const float* __restrict__ u, const float* __restrict__ scale,
    float* __restrict__ W) {
    __shared__ int   s_idx[SPP];
    __shared__ float s_cf[SPP];
    __shared__ int   s_cnt;
    const int g    = blockIdx.x / NPART;
    const int part = blockIdx.x % NPART;
    const int t    = threadIdx.x;
    if (t == 0) s_cnt = 0;
    __syncthreads();
    const int s_beg = part * SPP;
    const int s_end = min(NS, s_beg + SPP);
    for (int s = s_beg + t; s < s_end; s += 256) {
        int4 cl = cells[s]; float4 cf = coefs[s];
        float c = 0.f;
        if (cl.x == g) c += cf.x;
        if (cl.y == g) c += cf.y;
        if (cl.z == g) c += cf.z;
        if (cl.w == g) c += cf.w;
        if (c != 0.f) {
            int idx = atomicAdd(&s_cnt, 1);
            s_idx[idx] = s;
            s_cf[idx]  = c;
        }
    }
    __syncthreads();
    const int cnt = s_cnt;
    float a0 = 0.f, a1 = 0.f, a2 = 0.f;
    for (int j = 0; j < cnt; ++j) {
        const int   s  = s_idx[j];
        const float c  = s_cf[j];
        const int   ch = s >> 4;           // s / CS
        const float* ur = u     + (long)s*DD;
        const float* sr = scale + (long)ch*DD;
        a0 += c * sr[t      ] * ur[t      ];
        a1 += c * sr[t + 256] * ur[t + 256];
        a2 += c * sr[t + 512] * ur[t + 512];
    }
    atomicAdd(&W[g*DD + t      ], a0);
    atomicAdd(&W[g*DD + t + 256], a1);
    atomicAdd(&W[g*DD + t + 512], a2);
}

// ---------------------------------------------------------------------------
// k4 final: out[n,d] = sum_g W[g,d] * T[g,n,d]
// ---------------------------------------------------------------------------
__global__ __launch_bounds__(256) void final_kernel(
    const float* __restrict__ emb, const float* __restrict__ W,
    float* __restrict__ out) {
    const int n    = blockIdx.x / 3;
    const int part = blockIdx.x % 3;
    const int d    = part*256 + threadIdx.x;
    float a0 = 0.f, a1 = 0.f, a2 = 0.f, a3 = 0.f;
    int g = 0;
    #pragma unroll 4
    for (; g + 4 <= 80; g += 4) {
        a0 += W[(g+0)*DD + d] * emb[((g+0)*NCH + n)*DD + d];
        a1 += W[(g+1)*DD + d] * emb[((g+1)*NCH + n)*DD + d];
        a2 += W[(g+2)*DD + d] * emb[((g+2)*NCH + n)*DD + d];
        a3 += W[(g+3)*DD + d] * emb[((g+3)*NCH + n)*DD + d];
    }
    a0 += W[80*DD + d] * emb[(80*NCH + n)*DD + d];
    out[n*DD + d] = (a0 + a1) + (a2 + a3);
}

// ---------------------------------------------------------------------------
extern "C" void kernel_launch(void* const* d_in, const int* in_sizes, int n_in,
                              void* d_out, int out_size, void* d_ws, size_t ws_size,
                              hipStream_t stream) {
    const float* samples    = (const float*)d_in[0];
    const float* last_point = (const float*)d_in[1];
    const float* emb        = (const float*)d_in[2];
    float* out = (float*)d_out;

    char* ws = (char*)d_ws;
    int4*   cells = (int4*)ws;     ws += (size_t)NS*sizeof(int4);
    float4* coefs = (float4*)ws;   ws += (size_t)NS*sizeof(float4);
    float*  Ebuf  = (float*)ws;    ws += (size_t)NBLK*DD*sizeof(float);
    float*  scale = (float*)ws;    ws += (size_t)NBLK*DD*sizeof(float);
    float*  Wbuf  = (float*)ws;    ws += (size_t)NW*sizeof(float);
    float*  umat  = (float*)ws;    ws += (size_t)NS*DD*sizeof(float);

    pass1_kernel<<<NBLK, NTHR, 0, stream>>>(samples, last_point, emb,
                                            cells, coefs, umat, Ebuf, Wbuf);
    scan_kernel<<<DD, 64, 0, stream>>>(Ebuf, scale);
    wacc_kernel<<<NACC, 256, 0, stream>>>(cells, coefs, umat, scale, Wbuf);
    final_kernel<<<NH*3, 256, 0, stream>>>(emb, Wbuf, out);
}